// Round 6
// baseline (187.554 us; speedup 1.0000x reference)
//
#include <hip/hip_runtime.h>
#include <hip/hip_bf16.h>

#define B_  16
#define N_  16
#define H_  640
#define W_  640
#define HP_ 300
#define WP_ 300
#define IMG_FLOATS (H_ * W_ * 3)              // 1,228,800
#define ALL_FLOATS (B_ * IMG_FLOATS)          // 19,660,800
#define PBOX_OFF   ALL_FLOATS
#define IMG_F4     (IMG_FLOATS / 4)           // 307,200
#define F4_PER_BLOCK 2048
#define BLOCKS_PER_IMG (IMG_F4 / F4_PER_BLOCK)   // 150
#define CHUNKS_PER_IMG (IMG_F4 / 64)          // 4800 (one 16-bit mask per 64-f4 wave chunk)
#define CM_OFF_BYTES 4096                     // info: 256 entries x int4 = 4096 B

typedef float f4v __attribute__((ext_vector_type(4)));

// d_ws layout: [0,4096): boxinfo int4 (y0,x0,s,flags) x 256
//              [4096, 4096+153600): chunk mask table uint16 [B][4800]

__global__ __launch_bounds__(256) void prep_kernel(
    const float* __restrict__ boxes,           // [B,N,4]
    const unsigned char* __restrict__ dec_raw, // [B,N,3] bool/int32/float32 (detected)
    float* __restrict__ pboxes_out,            // [B,N,4] -> d_out tail
    int* __restrict__ info,                    // 256 x int4
    unsigned short* __restrict__ cm,           // [B][4800]
    int build_cm)
{
    int b = blockIdx.x;           // one block per image
    int t = threadIdx.x;
    __shared__ int s_nz, s_fp;
    __shared__ int ly0[N_], lx0[N_], ls[N_], lfl[N_];
    if (t == 0) { s_nz = 0; s_fp = 0; }
    __syncthreads();
    int nz = 0, fp = 0;
    for (int i = t; i < B_ * N_ * 3; i += 256) {   // first 768 bytes valid under all layouts
        unsigned char by = dec_raw[i];
        if ((i & 3) && by) nz = 1;
        if (by == 0x3F || by == 0x80) fp = 1;
    }
    if (nz) atomicOr(&s_nz, 1);
    if (fp) atomicOr(&s_fp, 1);
    __syncthreads();
    int mode = !s_nz ? 1 : (s_fp ? 2 : 0);   // 0=bool8, 1=int32, 2=float32

    if (t < N_) {
        int e = b * N_ + t;
        float ymin = boxes[e*4+0], xmin = boxes[e*4+1];
        float h = boxes[e*4+2], w = boxes[e*4+3];
        float ph = h * 0.2f;
        float pw = 1.0f * ph;                 // ASPECT=1
        float y0 = ymin + h * 0.5f;
        float x0 = xmin + w * 0.5f;
        if (y0 + ph > (float)H_) y0 = (float)H_ - ph;
        if (x0 + pw > (float)W_) x0 = (float)W_ - pw;
        pboxes_out[e*4+0] = y0; pboxes_out[e*4+1] = x0;
        pboxes_out[e*4+2] = ph; pboxes_out[e*4+3] = pw;

        int y0i = (int)y0, x0i = (int)x0;     // tf.cast truncation
        int phi = (int)ph, pwi = (int)pw;
        int valid = (phi * pwi) > 400;        // AREA_THRESH
        int s = phi > 1 ? phi : 1;

        int d0, d1, d2;
        if (mode == 0) {
            d0 = dec_raw[e*3+0] != 0; d1 = dec_raw[e*3+1] != 0; d2 = dec_raw[e*3+2] != 0;
        } else if (mode == 1) {
            const int* di = (const int*)dec_raw;
            d0 = di[e*3+0] != 0; d1 = di[e*3+1] != 0; d2 = di[e*3+2] != 0;
        } else {
            const float* df = (const float*)dec_raw;
            d0 = df[e*3+0] != 0.0f; d1 = df[e*3+1] != 0.0f; d2 = df[e*3+2] != 0.0f;
        }
        int flags = valid | (d0 << 1) | (d1 << 2) | (d2 << 3);
        ly0[t] = y0i; lx0[t] = x0i; ls[t] = s; lfl[t] = flags;
        int* ei = info + e * 4;
        ei[0] = y0i; ei[1] = x0i; ei[2] = s; ei[3] = flags;
    }
    __syncthreads();

    if (build_cm) {
        unsigned short* cmb = cm + b * CHUNKS_PER_IMG;
        for (int c = t; c < CHUNKS_PER_IMG; c += 256) {
            // chunk c covers floats [256c, 256c+256) -> pixels px_lo..px_hi (<=2 rows)
            int px_lo = (256 * c) / 3;
            int px_hi = (256 * c + 255) / 3;
            int ry0 = px_lo / W_, ry1 = px_hi / W_;
            int cx0 = px_lo - ry0 * W_;
            int cx1 = px_hi - ry1 * W_;
            unsigned m16 = 0;
            for (int m = 0; m < N_; ++m) {
                if (!(lfl[m] & 1)) continue;
                int s = ls[m];
                int hit = 0;
                int hi0 = (ry0 == ry1) ? cx1 : (W_ - 1);   // segment on row ry0
                if ((unsigned)(ry0 - ly0[m]) < (unsigned)s &&
                    lx0[m] <= hi0 && lx0[m] + s > cx0) hit = 1;
                if (ry1 != ry0) {                           // segment on row ry1
                    if ((unsigned)(ry1 - ly0[m]) < (unsigned)s &&
                        lx0[m] <= cx1 && lx0[m] + s > 0) hit = 1;
                }
                if (hit) m16 |= 1u << m;
            }
            cmb[c] = (unsigned short)m16;
        }
    }
}

__device__ __forceinline__ int sample_px(
    int p, unsigned mask, const int4* __restrict__ binfo,   // this image's 16 boxes
    const float* __restrict__ patch,
    float& cr, float& cg, float& cb)
{
    int gy = p / W_;
    int gx = p - gy * W_;
    while (mask) {
        int m = 31 - __clz(mask);            // highest index = last write wins
        int4 e = binfo[m];                   // y0,x0,s,flags (L2-broadcast)
        int s = e.z;
        int ry = gy - e.x, rx = gx - e.y;
        if ((unsigned)ry < (unsigned)s && (unsigned)rx < (unsigned)s) {
            int fl = e.w;
            // invert transforms: flip_ud, flip_lr, then rot90 (CCW)
            int iy2 = (fl & 8) ? (s - 1 - ry) : ry;
            int ix2 = (fl & 4) ? (s - 1 - rx) : rx;
            int ty  = (fl & 2) ? ix2 : iy2;
            int tx  = (fl & 2) ? (s - 1 - iy2) : ix2;
            float sf  = (float)s;
            float sc  = (float)HP_ / sf;
            float sy = ((float)ty + 0.5f) * sc - 0.5f;
            float sx = ((float)tx + 0.5f) * sc - 0.5f;
            sy = fminf(fmaxf(sy, 0.0f), (float)(HP_ - 1));
            sx = fminf(fmaxf(sx, 0.0f), (float)(WP_ - 1));
            int yy0 = (int)sy;               // sy >= 0 -> trunc == floor
            int xx0 = (int)sx;
            int yy1 = yy0 + 1 < HP_ - 1 ? yy0 + 1 : HP_ - 1;
            int xx1 = xx0 + 1 < WP_ - 1 ? xx0 + 1 : WP_ - 1;
            float wy = sy - (float)yy0;
            float wx = sx - (float)xx0;
            const float* p00 = patch + (yy0 * WP_ + xx0) * 3;
            const float* p01 = patch + (yy0 * WP_ + xx1) * 3;
            const float* p10 = patch + (yy1 * WP_ + xx0) * 3;
            const float* p11 = patch + (yy1 * WP_ + xx1) * 3;
            float t0 = p00[0]*(1.f-wx) + p01[0]*wx;
            float b0 = p10[0]*(1.f-wx) + p11[0]*wx;
            cr = t0*(1.f-wy) + b0*wy;
            float t1 = p00[1]*(1.f-wx) + p01[1]*wx;
            float b1 = p10[1]*(1.f-wx) + p11[1]*wx;
            cg = t1*(1.f-wy) + b1*wy;
            float t2 = p00[2]*(1.f-wx) + p01[2]*wx;
            float b2 = p10[2]*(1.f-wx) + p11[2]*wx;
            cb = t2*(1.f-wy) + b2*wy;
            return 1;
        }
        mask &= ~(1u << m);
    }
    return 0;
}

__device__ __forceinline__ f4v proc_f4(
    f4v v, int f, unsigned mask,           // f = float4 index within the image
    const int4* __restrict__ binfo,
    const float* __restrict__ patch)
{
    int p0 = f + f / 3;                    // (4f)/3; floats 4f..4f+3 span pixels p0,p0+1
    float c00, c01, c02, c10, c11, c12;
    int h0 = sample_px(p0,     mask, binfo, patch, c00, c01, c02);
    int h1 = sample_px(p0 + 1, mask, binfo, patch, c10, c11, c12);
    if (!(h0 | h1)) return v;

    int r = f % 3;                         // (4f)%3 pattern selector -> all-static indexing
    if (r == 0) {
        if (h0) { v.x = c00; v.y = c01; v.z = c02; }
        if (h1) { v.w = c10; }
    } else if (r == 1) {
        if (h0) { v.x = c01; v.y = c02; }
        if (h1) { v.z = c10; v.w = c11; }
    } else {
        if (h0) { v.x = c02; }
        if (h1) { v.y = c10; v.z = c11; v.w = c12; }
    }
    return v;
}

// Fallback (no workspace for the table): exact chunk test from global box info.
__device__ __forceinline__ unsigned chunk_mask_inline(
    int c, const int4* __restrict__ binfo)
{
    int px_lo = (256 * c) / 3;
    int px_hi = (256 * c + 255) / 3;
    int ry0 = px_lo / W_, ry1 = px_hi / W_;
    int cx0 = px_lo - ry0 * W_;
    int cx1 = px_hi - ry1 * W_;
    unsigned m16 = 0;
    for (int m = 0; m < N_; ++m) {
        int4 e = binfo[m];
        if (!(e.w & 1)) continue;
        int s = e.z;
        int hit = 0;
        int hi0 = (ry0 == ry1) ? cx1 : (W_ - 1);
        if ((unsigned)(ry0 - e.x) < (unsigned)s && e.y <= hi0 && e.y + s > cx0) hit = 1;
        if (ry1 != ry0 && (unsigned)(ry1 - e.x) < (unsigned)s && e.y <= cx1 && e.y + s > 0) hit = 1;
        if (hit) m16 |= 1u << m;
    }
    return m16;
}

__global__ __launch_bounds__(256) void fused_kernel(
    const f4v* __restrict__ images4,
    const float* __restrict__ patch,
    const int4* __restrict__ info,              // [B*N] (y0,x0,s,flags)
    const unsigned short* __restrict__ cm,      // [B][4800]
    f4v* __restrict__ out4,
    int use_tab)
{
    int blk = blockIdx.x;
    int b = blk / BLOCKS_PER_IMG;
    int blkLocal = blk - b * BLOCKS_PER_IMG;
    int t = threadIdx.x;

    const int4* binfo = info + b * N_;
    const unsigned short* cmb = cm + b * CHUNKS_PER_IMG;

    size_t ibase = (size_t)b * IMG_F4 + (size_t)blkLocal * F4_PER_BLOCK + t;
    int    fbase = blkLocal * F4_PER_BLOCK + t;       // image-local f4 index (+ j*256)
    int    cbase = blkLocal * 32 + (t >> 6);          // wave-uniform chunk id (+ j*4)

    // chunk masks: one uniform 2B L2 load per chunk
    unsigned mk[8];
    if (use_tab) {
        #pragma unroll
        for (int j = 0; j < 8; ++j) mk[j] = cmb[cbase + 4 * j];
    } else {
        #pragma unroll
        for (int j = 0; j < 8; ++j) mk[j] = chunk_mask_inline(cbase + 4 * j, binfo);
    }

    // deep-MLP streaming: 8 outstanding 16B loads per lane
    f4v v[8];
    #pragma unroll
    for (int j = 0; j < 8; ++j) v[j] = images4[ibase + (size_t)(j * 256)];

    #pragma unroll
    for (int j = 0; j < 8; ++j)
        if (mk[j]) v[j] = proc_f4(v[j], fbase + j * 256, mk[j], binfo, patch);

    // nontemporal: output has zero reuse; keep input resident in L3
    #pragma unroll
    for (int j = 0; j < 8; ++j)
        __builtin_nontemporal_store(v[j], (f4v*)&out4[ibase + (size_t)(j * 256)]);
}

extern "C" void kernel_launch(void* const* d_in, const int* in_sizes, int n_in,
                              void* d_out, int out_size, void* d_ws, size_t ws_size,
                              hipStream_t stream) {
    const float*         boxes   = (const float*)d_in[0];
    const float*         images  = (const float*)d_in[1];
    const float*         patch   = (const float*)d_in[2];
    const unsigned char* dec_raw = (const unsigned char*)d_in[3];

    float* out    = (float*)d_out;
    float* pboxes = out + PBOX_OFF;
    int*   info   = (int*)d_ws;
    unsigned short* cm = (unsigned short*)((char*)d_ws + CM_OFF_BYTES);
    size_t need = CM_OFF_BYTES + (size_t)B_ * CHUNKS_PER_IMG * sizeof(unsigned short);
    int use_tab = (ws_size >= need) ? 1 : 0;

    prep_kernel<<<B_, 256, 0, stream>>>(boxes, dec_raw, pboxes, info, cm, use_tab);
    fused_kernel<<<B_ * BLOCKS_PER_IMG, 256, 0, stream>>>(
        (const f4v*)images, patch, (const int4*)info, cm, (f4v*)out, use_tab);
}

// Round 7
// 185.589 us; speedup vs baseline: 1.0106x; 1.0106x over previous
//
#include <hip/hip_runtime.h>
#include <hip/hip_bf16.h>

#define B_  16
#define N_  16
#define H_  640
#define W_  640
#define HP_ 300
#define WP_ 300
#define IMG_FLOATS (H_ * W_ * 3)              // 1,228,800
#define ALL_FLOATS (B_ * IMG_FLOATS)          // 19,660,800
#define PBOX_OFF   ALL_FLOATS
#define IMG_F4     (IMG_FLOATS / 4)           // 307,200
#define F4_PER_BLOCK 2048
#define BLOCKS_PER_IMG (IMG_F4 / F4_PER_BLOCK)   // 150
#define CHUNKS_PER_IMG (IMG_F4 / 64)          // 4800 (one 16-bit mask per 64-f4 wave chunk)
#define CM_OFF_BYTES 4096                     // info: 256 entries x int4 = 4096 B

typedef float f4v __attribute__((ext_vector_type(4)));

// d_ws layout: [0,4096): boxinfo int4 (y0,x0,s,flags) x 256
//              [4096, 4096+153600): chunk mask table uint16 [B][4800]

__global__ __launch_bounds__(256) void prep_kernel(
    const float* __restrict__ boxes,           // [B,N,4]
    const unsigned char* __restrict__ dec_raw, // [B,N,3] bool/int32/float32 (detected)
    float* __restrict__ pboxes_out,            // [B,N,4] -> d_out tail
    int* __restrict__ info,                    // 256 x int4
    unsigned short* __restrict__ cm,           // [B][4800]
    int build_cm)
{
    int b = blockIdx.x;           // one block per image
    int t = threadIdx.x;
    __shared__ int s_nz, s_fp;
    __shared__ int ly0[N_], lx0[N_], ls[N_], lfl[N_];
    if (t == 0) { s_nz = 0; s_fp = 0; }
    __syncthreads();
    int nz = 0, fp = 0;
    for (int i = t; i < B_ * N_ * 3; i += 256) {   // first 768 bytes valid under all layouts
        unsigned char by = dec_raw[i];
        if ((i & 3) && by) nz = 1;
        if (by == 0x3F || by == 0x80) fp = 1;
    }
    if (nz) atomicOr(&s_nz, 1);
    if (fp) atomicOr(&s_fp, 1);
    __syncthreads();
    int mode = !s_nz ? 1 : (s_fp ? 2 : 0);   // 0=bool8, 1=int32, 2=float32

    if (t < N_) {
        int e = b * N_ + t;
        float ymin = boxes[e*4+0], xmin = boxes[e*4+1];
        float h = boxes[e*4+2], w = boxes[e*4+3];
        float ph = h * 0.2f;
        float pw = 1.0f * ph;                 // ASPECT=1
        float y0 = ymin + h * 0.5f;
        float x0 = xmin + w * 0.5f;
        if (y0 + ph > (float)H_) y0 = (float)H_ - ph;
        if (x0 + pw > (float)W_) x0 = (float)W_ - pw;
        pboxes_out[e*4+0] = y0; pboxes_out[e*4+1] = x0;
        pboxes_out[e*4+2] = ph; pboxes_out[e*4+3] = pw;

        int y0i = (int)y0, x0i = (int)x0;     // tf.cast truncation
        int phi = (int)ph, pwi = (int)pw;
        int valid = (phi * pwi) > 400;        // AREA_THRESH
        int s = phi > 1 ? phi : 1;

        int d0, d1, d2;
        if (mode == 0) {
            d0 = dec_raw[e*3+0] != 0; d1 = dec_raw[e*3+1] != 0; d2 = dec_raw[e*3+2] != 0;
        } else if (mode == 1) {
            const int* di = (const int*)dec_raw;
            d0 = di[e*3+0] != 0; d1 = di[e*3+1] != 0; d2 = di[e*3+2] != 0;
        } else {
            const float* df = (const float*)dec_raw;
            d0 = df[e*3+0] != 0.0f; d1 = df[e*3+1] != 0.0f; d2 = df[e*3+2] != 0.0f;
        }
        int flags = valid | (d0 << 1) | (d1 << 2) | (d2 << 3);
        ly0[t] = y0i; lx0[t] = x0i; ls[t] = s; lfl[t] = flags;
        int* ei = info + e * 4;
        ei[0] = y0i; ei[1] = x0i; ei[2] = s; ei[3] = flags;
    }
    __syncthreads();

    if (build_cm) {
        unsigned short* cmb = cm + b * CHUNKS_PER_IMG;
        for (int c = t; c < CHUNKS_PER_IMG; c += 256) {
            // chunk c covers floats [256c, 256c+256) -> pixels px_lo..px_hi (<=2 rows)
            int px_lo = (256 * c) / 3;
            int px_hi = (256 * c + 255) / 3;
            int ry0 = px_lo / W_, ry1 = px_hi / W_;
            int cx0 = px_lo - ry0 * W_;
            int cx1 = px_hi - ry1 * W_;
            unsigned m16 = 0;
            for (int m = 0; m < N_; ++m) {
                if (!(lfl[m] & 1)) continue;
                int s = ls[m];
                int hit = 0;
                int hi0 = (ry0 == ry1) ? cx1 : (W_ - 1);   // segment on row ry0
                if ((unsigned)(ry0 - ly0[m]) < (unsigned)s &&
                    lx0[m] <= hi0 && lx0[m] + s > cx0) hit = 1;
                if (ry1 != ry0) {                           // segment on row ry1
                    if ((unsigned)(ry1 - ly0[m]) < (unsigned)s &&
                        lx0[m] <= cx1 && lx0[m] + s > 0) hit = 1;
                }
                if (hit) m16 |= 1u << m;
            }
            cmb[c] = (unsigned short)m16;
        }
    }
}

__device__ __forceinline__ int sample_px(
    int p, unsigned mask, const int4* __restrict__ binfo,   // this image's 16 boxes
    const float* __restrict__ patch,
    float& cr, float& cg, float& cb)
{
    int gy = p / W_;
    int gx = p - gy * W_;
    while (mask) {
        int m = 31 - __clz(mask);            // highest index = last write wins
        int4 e = binfo[m];                   // y0,x0,s,flags (L2-broadcast)
        int s = e.z;
        int ry = gy - e.x, rx = gx - e.y;
        if ((unsigned)ry < (unsigned)s && (unsigned)rx < (unsigned)s) {
            int fl = e.w;
            // invert transforms: flip_ud, flip_lr, then rot90 (CCW)
            int iy2 = (fl & 8) ? (s - 1 - ry) : ry;
            int ix2 = (fl & 4) ? (s - 1 - rx) : rx;
            int ty  = (fl & 2) ? ix2 : iy2;
            int tx  = (fl & 2) ? (s - 1 - iy2) : ix2;
            float sf  = (float)s;
            float sc  = (float)HP_ / sf;
            float sy = ((float)ty + 0.5f) * sc - 0.5f;
            float sx = ((float)tx + 0.5f) * sc - 0.5f;
            sy = fminf(fmaxf(sy, 0.0f), (float)(HP_ - 1));
            sx = fminf(fmaxf(sx, 0.0f), (float)(WP_ - 1));
            int yy0 = (int)sy;               // sy >= 0 -> trunc == floor
            int xx0 = (int)sx;
            int yy1 = yy0 + 1 < HP_ - 1 ? yy0 + 1 : HP_ - 1;
            int xx1 = xx0 + 1 < WP_ - 1 ? xx0 + 1 : WP_ - 1;
            float wy = sy - (float)yy0;
            float wx = sx - (float)xx0;
            const float* p00 = patch + (yy0 * WP_ + xx0) * 3;
            const float* p01 = patch + (yy0 * WP_ + xx1) * 3;
            const float* p10 = patch + (yy1 * WP_ + xx0) * 3;
            const float* p11 = patch + (yy1 * WP_ + xx1) * 3;
            float t0 = p00[0]*(1.f-wx) + p01[0]*wx;
            float b0 = p10[0]*(1.f-wx) + p11[0]*wx;
            cr = t0*(1.f-wy) + b0*wy;
            float t1 = p00[1]*(1.f-wx) + p01[1]*wx;
            float b1 = p10[1]*(1.f-wx) + p11[1]*wx;
            cg = t1*(1.f-wy) + b1*wy;
            float t2 = p00[2]*(1.f-wx) + p01[2]*wx;
            float b2 = p10[2]*(1.f-wx) + p11[2]*wx;
            cb = t2*(1.f-wy) + b2*wy;
            return 1;
        }
        mask &= ~(1u << m);
    }
    return 0;
}

__device__ __forceinline__ f4v proc_f4(
    f4v v, int f, unsigned mask,           // f = float4 index within the image
    const int4* __restrict__ binfo,
    const float* __restrict__ patch)
{
    int p0 = f + f / 3;                    // (4f)/3; floats 4f..4f+3 span pixels p0,p0+1
    float c00, c01, c02, c10, c11, c12;
    int h0 = sample_px(p0,     mask, binfo, patch, c00, c01, c02);
    int h1 = sample_px(p0 + 1, mask, binfo, patch, c10, c11, c12);
    if (!(h0 | h1)) return v;

    int r = f % 3;                         // (4f)%3 pattern selector -> all-static indexing
    if (r == 0) {
        if (h0) { v.x = c00; v.y = c01; v.z = c02; }
        if (h1) { v.w = c10; }
    } else if (r == 1) {
        if (h0) { v.x = c01; v.y = c02; }
        if (h1) { v.z = c10; v.w = c11; }
    } else {
        if (h0) { v.x = c02; }
        if (h1) { v.y = c10; v.z = c11; v.w = c12; }
    }
    return v;
}

// Fallback (no workspace for the table): exact chunk test from global box info.
__device__ __forceinline__ unsigned chunk_mask_inline(
    int c, const int4* __restrict__ binfo)
{
    int px_lo = (256 * c) / 3;
    int px_hi = (256 * c + 255) / 3;
    int ry0 = px_lo / W_, ry1 = px_hi / W_;
    int cx0 = px_lo - ry0 * W_;
    int cx1 = px_hi - ry1 * W_;
    unsigned m16 = 0;
    for (int m = 0; m < N_; ++m) {
        int4 e = binfo[m];
        if (!(e.w & 1)) continue;
        int s = e.z;
        int hit = 0;
        int hi0 = (ry0 == ry1) ? cx1 : (W_ - 1);
        if ((unsigned)(ry0 - e.x) < (unsigned)s && e.y <= hi0 && e.y + s > cx0) hit = 1;
        if (ry1 != ry0 && (unsigned)(ry1 - e.x) < (unsigned)s && e.y <= cx1 && e.y + s > 0) hit = 1;
        if (hit) m16 |= 1u << m;
    }
    return m16;
}

__global__ __launch_bounds__(256) void fused_kernel(
    const f4v* __restrict__ images4,
    const float* __restrict__ patch,
    const int4* __restrict__ info,              // [B*N] (y0,x0,s,flags)
    const unsigned short* __restrict__ cm,      // [B][4800]
    f4v* __restrict__ out4,
    int use_tab)
{
    int blk = blockIdx.x;
    int b = blk / BLOCKS_PER_IMG;
    int blkLocal = blk - b * BLOCKS_PER_IMG;
    int t = threadIdx.x;

    const int4* binfo = info + b * N_;
    const unsigned short* cmb = cm + b * CHUNKS_PER_IMG;

    size_t ibase = (size_t)b * IMG_F4 + (size_t)blkLocal * F4_PER_BLOCK + t;
    int    fbase = blkLocal * F4_PER_BLOCK + t;       // image-local f4 index (+ j*256)
    int    cbase = blkLocal * 32 + (t >> 6);          // wave-uniform chunk id (+ j*4)

    // chunk masks: one uniform 2B L2 load per chunk
    unsigned mk[8];
    if (use_tab) {
        #pragma unroll
        for (int j = 0; j < 8; ++j) mk[j] = cmb[cbase + 4 * j];
    } else {
        #pragma unroll
        for (int j = 0; j < 8; ++j) mk[j] = chunk_mask_inline(cbase + 4 * j, binfo);
    }

    // deep-MLP streaming: 8 outstanding 16B loads per lane
    f4v v[8];
    #pragma unroll
    for (int j = 0; j < 8; ++j) v[j] = images4[ibase + (size_t)(j * 256)];

    #pragma unroll
    for (int j = 0; j < 8; ++j)
        if (mk[j]) v[j] = proc_f4(v[j], fbase + j * 256, mk[j], binfo, patch);

    // plain stores: keep L2 write-combining (nt stores regressed R6: 48.5->55.4 us)
    #pragma unroll
    for (int j = 0; j < 8; ++j)
        out4[ibase + (size_t)(j * 256)] = v[j];
}

extern "C" void kernel_launch(void* const* d_in, const int* in_sizes, int n_in,
                              void* d_out, int out_size, void* d_ws, size_t ws_size,
                              hipStream_t stream) {
    const float*         boxes   = (const float*)d_in[0];
    const float*         images  = (const float*)d_in[1];
    const float*         patch   = (const float*)d_in[2];
    const unsigned char* dec_raw = (const unsigned char*)d_in[3];

    float* out    = (float*)d_out;
    float* pboxes = out + PBOX_OFF;
    int*   info   = (int*)d_ws;
    unsigned short* cm = (unsigned short*)((char*)d_ws + CM_OFF_BYTES);
    size_t need = CM_OFF_BYTES + (size_t)B_ * CHUNKS_PER_IMG * sizeof(unsigned short);
    int use_tab = (ws_size >= need) ? 1 : 0;

    prep_kernel<<<B_, 256, 0, stream>>>(boxes, dec_raw, pboxes, info, cm, use_tab);
    fused_kernel<<<B_ * BLOCKS_PER_IMG, 256, 0, stream>>>(
        (const f4v*)images, patch, (const int4*)info, cm, (f4v*)out, use_tab);
}